// Round 1
// baseline (153.439 us; speedup 1.0000x reference)
//
#include <hip/hip_runtime.h>

typedef unsigned short u16;
typedef unsigned int   u32;

typedef __bf16 bf16x8 __attribute__((ext_vector_type(8)));
typedef float  f32x4  __attribute__((ext_vector_type(4)));

#define B_DIM 4
#define T_DIM 8192
#define D_DIM 512
#define M_DIM (B_DIM * T_DIM)   // 32768
#define K_DIM D_DIM             // 512
#define NC    256               // chunks along T
#define LCH   32                // chunk length (NC*LCH == T_DIM)

__device__ __forceinline__ u16 f2bf(float f) {
  u32 u = __float_as_uint(f);
  u32 r = (u + 0x7FFFu + ((u >> 16) & 1u)) >> 16;   // RNE
  return (u16)r;
}
__device__ __forceinline__ float bf2f(u16 b) {
  return __uint_as_float(((u32)b) << 16);
}

// ---------------- conversion kernels ----------------

__global__ void convert_x(const float4* __restrict__ in, u16* __restrict__ out, int n4) {
  int i = blockIdx.x * blockDim.x + threadIdx.x;
  int stride = gridDim.x * blockDim.x;
  for (; i < n4; i += stride) {
    float4 f = in[i];
    u32 w0 = (u32)f2bf(f.x) | ((u32)f2bf(f.y) << 16);
    u32 w1 = (u32)f2bf(f.z) | ((u32)f2bf(f.w) << 16);
    *reinterpret_cast<uint2*>(out + (size_t)i * 4) = make_uint2(w0, w1);
  }
}

// W [K=512][N=1024] fp32 -> wt [N=1024][K=512] bf16 (transposed)
__global__ void convert_wt(const float* __restrict__ W, u16* __restrict__ wt) {
  int idx = blockIdx.x * blockDim.x + threadIdx.x;  // 65536 threads
  int n  = idx & 1023;
  int k0 = (idx >> 10) * 8;                          // 0..63 blocks of 8 k
  float f[8];
#pragma unroll
  for (int j = 0; j < 8; ++j) f[j] = W[(size_t)(k0 + j) * 1024 + n];
  u32 w[4];
#pragma unroll
  for (int j = 0; j < 4; ++j)
    w[j] = (u32)f2bf(f[2 * j]) | ((u32)f2bf(f[2 * j + 1]) << 16);
  *reinterpret_cast<uint4*>(wt + (size_t)n * 512 + k0) = make_uint4(w[0], w[1], w[2], w[3]);
}

// ---------------- GEMM + fused activation epilogue ----------------
// Block tile: 128 M-rows x 64 d-channels (stages 128 W-cols: 64 hidden + 64 gate).
// 4 waves, each wave: 32 M-rows x all 128 cols -> acc[2][8] of 16x16 frags.
// Pairing: hidden = acc[m][n], gate = acc[m][n+4] (same lane/row/col-within-16).

#define BK    32
#define LDSK  40   // padded leading dim (bf16 elems)

__global__ __launch_bounds__(256) void gemm_act(const u16* __restrict__ xb,
                                                const u16* __restrict__ wt,
                                                u16* __restrict__ a_buf,
                                                u16* __restrict__ v_buf) {
  __shared__ u16 As[128][LDSK];
  __shared__ u16 Bs[128][LDSK];

  const int tid  = threadIdx.x;
  const int lane = tid & 63;
  const int wave = tid >> 6;        // 0..3
  const int l15  = lane & 15;
  const int lh   = lane >> 4;       // 0..3
  const int m_base = blockIdx.x * 128;
  const int d0     = blockIdx.y * 64;

  const int srow  = tid >> 2;       // 0..63
  const int scol8 = (tid & 3) * 8;  // bf16 offset within 32-k row

  f32x4 acc[2][8];
#pragma unroll
  for (int m = 0; m < 2; ++m)
#pragma unroll
    for (int n = 0; n < 8; ++n)
      acc[m][n] = (f32x4){0.f, 0.f, 0.f, 0.f};

  for (int k0 = 0; k0 < K_DIM; k0 += BK) {
    __syncthreads();
#pragma unroll
    for (int i = 0; i < 2; ++i) {
      int row = srow + i * 64;
      uint4 va = *reinterpret_cast<const uint4*>(xb + (size_t)(m_base + row) * K_DIM + k0 + scol8);
      *reinterpret_cast<uint4*>(&As[row][scol8]) = va;
      int gn = (row < 64) ? (d0 + row) : (512 + d0 + (row - 64));
      uint4 vb = *reinterpret_cast<const uint4*>(wt + (size_t)gn * K_DIM + k0 + scol8);
      *reinterpret_cast<uint4*>(&Bs[row][scol8]) = vb;
    }
    __syncthreads();

    bf16x8 af[2], bfr[8];
#pragma unroll
    for (int m = 0; m < 2; ++m)
      af[m] = *reinterpret_cast<const bf16x8*>(&As[wave * 32 + m * 16 + l15][lh * 8]);
#pragma unroll
    for (int n = 0; n < 8; ++n)
      bfr[n] = *reinterpret_cast<const bf16x8*>(&Bs[n * 16 + l15][lh * 8]);
#pragma unroll
    for (int m = 0; m < 2; ++m)
#pragma unroll
      for (int n = 0; n < 8; ++n)
        acc[m][n] = __builtin_amdgcn_mfma_f32_16x16x32_bf16(af[m], bfr[n], acc[m][n], 0, 0, 0);
  }

  // epilogue: a = sigmoid(-gate), v = sigmoid(gate)*g(hidden)
#pragma unroll
  for (int m = 0; m < 2; ++m) {
#pragma unroll
    for (int n = 0; n < 4; ++n) {
#pragma unroll
      for (int r = 0; r < 4; ++r) {
        float hid = acc[m][n][r];
        float gt  = acc[m][n + 4][r];
        float e   = __expf(gt);
        float a   = 1.f / (1.f + e);   // sigmoid(-gate) = 1 - z
        float z   = e / (1.f + e);     // sigmoid(gate)
        float g   = (hid >= 0.f) ? (hid + 0.5f) : (1.f / (1.f + __expf(-hid)));
        float v   = z * g;
        int row = m_base + wave * 32 + m * 16 + lh * 4 + r;
        int col = d0 + n * 16 + l15;
        size_t off = (size_t)row * D_DIM + col;
        a_buf[off] = f2bf(a);
        v_buf[off] = f2bf(v);
      }
    }
  }
}

// ---------------- chunked linear-recurrence scan ----------------
// h_t = a_t * h_{t-1} + v_t ; chunk transform h_out = A*h_in + B.

__global__ __launch_bounds__(128) void scan_pass1(const u16* __restrict__ a_buf,
                                                  const u16* __restrict__ v_buf,
                                                  float4* __restrict__ Asum,
                                                  float4* __restrict__ Bsum) {
  const int c = blockIdx.x;    // chunk
  const int b = blockIdx.y;    // batch
  const int d4 = threadIdx.x;  // 4 channels per thread
  float A[4] = {1.f, 1.f, 1.f, 1.f};
  float Bv[4] = {0.f, 0.f, 0.f, 0.f};
  size_t base = ((size_t)b * T_DIM + (size_t)c * LCH) * D_DIM + d4 * 4;
  for (int t = 0; t < LCH; ++t) {
    uint2 aw = *reinterpret_cast<const uint2*>(a_buf + base);
    uint2 vw = *reinterpret_cast<const uint2*>(v_buf + base);
    float av[4] = {bf2f(aw.x & 0xffff), bf2f(aw.x >> 16), bf2f(aw.y & 0xffff), bf2f(aw.y >> 16)};
    float vv[4] = {bf2f(vw.x & 0xffff), bf2f(vw.x >> 16), bf2f(vw.y & 0xffff), bf2f(vw.y >> 16)};
#pragma unroll
    for (int j = 0; j < 4; ++j) {
      Bv[j] = av[j] * Bv[j] + vv[j];
      A[j] *= av[j];
    }
    base += D_DIM;
  }
  size_t o = ((size_t)(b * NC + c)) * 128 + d4;
  Asum[o] = make_float4(A[0], A[1], A[2], A[3]);
  Bsum[o] = make_float4(Bv[0], Bv[1], Bv[2], Bv[3]);
}

__global__ void scan_pass2(const float4* __restrict__ Asum, const float4* __restrict__ Bsum,
                           float4* __restrict__ carry) {
  int idx = blockIdx.x * blockDim.x + threadIdx.x;  // 512 threads total
  int b  = idx >> 7;
  int d4 = idx & 127;
  float h[4] = {0.f, 0.f, 0.f, 0.f};
  for (int c = 0; c < NC; ++c) {
    size_t o = ((size_t)(b * NC + c)) * 128 + d4;
    carry[o] = make_float4(h[0], h[1], h[2], h[3]);
    float4 A  = Asum[o];
    float4 Bv = Bsum[o];
    h[0] = A.x * h[0] + Bv.x;
    h[1] = A.y * h[1] + Bv.y;
    h[2] = A.z * h[2] + Bv.z;
    h[3] = A.w * h[3] + Bv.w;
  }
}

__global__ __launch_bounds__(128) void scan_pass3(const u16* __restrict__ a_buf,
                                                  const u16* __restrict__ v_buf,
                                                  const float4* __restrict__ carry,
                                                  float4* __restrict__ out) {
  const int c = blockIdx.x;
  const int b = blockIdx.y;
  const int d4 = threadIdx.x;
  float4 hh = carry[((size_t)(b * NC + c)) * 128 + d4];
  float h[4] = {hh.x, hh.y, hh.z, hh.w};
  size_t base = ((size_t)b * T_DIM + (size_t)c * LCH) * D_DIM + d4 * 4;
  for (int t = 0; t < LCH; ++t) {
    uint2 aw = *reinterpret_cast<const uint2*>(a_buf + base);
    uint2 vw = *reinterpret_cast<const uint2*>(v_buf + base);
    float av[4] = {bf2f(aw.x & 0xffff), bf2f(aw.x >> 16), bf2f(aw.y & 0xffff), bf2f(aw.y >> 16)};
    float vv[4] = {bf2f(vw.x & 0xffff), bf2f(vw.x >> 16), bf2f(vw.y & 0xffff), bf2f(vw.y >> 16)};
#pragma unroll
    for (int j = 0; j < 4; ++j) h[j] = av[j] * h[j] + vv[j];
    out[base >> 2] = make_float4(h[0], h[1], h[2], h[3]);
    base += D_DIM;
  }
}

// ---------------- launch ----------------

extern "C" void kernel_launch(void* const* d_in, const int* in_sizes, int n_in,
                              void* d_out, int out_size, void* d_ws, size_t ws_size,
                              hipStream_t stream) {
  const float* x = (const float*)d_in[0];   // [4,8192,512]
  const float* W = (const float*)d_in[1];   // [512,1024]
  float* out = (float*)d_out;

  char* ws = (char*)d_ws;
  // layout (bytes):
  u16*   xb    = (u16*)(ws + 0);            // 33,554,432  x in bf16
  u16*   wtp   = (u16*)(ws + 33554432);     //  1,048,576  W^T in bf16
  u16*   a_buf = (u16*)(ws + 34603008);     // 33,554,432  a = 1-z (bf16)
  u16*   v_buf = (u16*)(ws + 68157440);     // 33,554,432  v = z*g (bf16)
  float4* Asum  = (float4*)(ws + 101711872); //  2,097,152
  float4* Bsum  = (float4*)(ws + 103809024); //  2,097,152
  float4* carry = (float4*)(ws + 105906176); //  2,097,152  (end 108,003,328)
  if (ws_size < 108003328ULL) return;        // insufficient workspace

  convert_x<<<2048, 256, 0, stream>>>((const float4*)x, xb, (M_DIM * K_DIM) / 4);
  convert_wt<<<256, 256, 0, stream>>>(W, wtp);
  gemm_act<<<dim3(M_DIM / 128, D_DIM / 64), 256, 0, stream>>>(xb, wtp, a_buf, v_buf);
  scan_pass1<<<dim3(NC, B_DIM), 128, 0, stream>>>(a_buf, v_buf, Asum, Bsum);
  scan_pass2<<<2, 256, 0, stream>>>(Asum, Bsum, carry);
  scan_pass3<<<dim3(NC, B_DIM), 128, 0, stream>>>(a_buf, v_buf, carry, (float4*)out);
}

// Round 4
// 136.931 us; speedup vs baseline: 1.1206x; 1.1206x over previous
//
#include <hip/hip_runtime.h>

typedef unsigned short u16;
typedef unsigned int   u32;

typedef __bf16 bf16x8 __attribute__((ext_vector_type(8)));
typedef float  f32x4  __attribute__((ext_vector_type(4)));

#define B_DIM 4
#define T_DIM 8192
#define D_DIM 512
#define M_DIM (B_DIM * T_DIM)   // 32768
#define K_DIM D_DIM             // 512
#define NC    256               // chunks along T
#define LCH   32                // chunk length (NC*LCH == T_DIM)

__device__ __forceinline__ u16 f2bf(float f) {
  u32 u = __float_as_uint(f);
  u32 r = (u + 0x7FFFu + ((u >> 16) & 1u)) >> 16;   // RNE
  return (u16)r;
}
__device__ __forceinline__ float bf2f(u16 b) {
  return __uint_as_float(((u32)b) << 16);
}

// async global->LDS, 16B per lane; lds base must be wave-uniform
__device__ __forceinline__ void gload_lds16(const u16* g, u16* lds) {
  __builtin_amdgcn_global_load_lds(
      (const __attribute__((address_space(1))) void*)g,
      (__attribute__((address_space(3))) void*)lds, 16, 0, 0);
}

// ---------------- conversion kernels ----------------

__global__ void convert_x(const float4* __restrict__ in, u16* __restrict__ out, int n4) {
  int i = blockIdx.x * blockDim.x + threadIdx.x;
  int stride = gridDim.x * blockDim.x;
  for (; i < n4; i += stride) {
    float4 f = in[i];
    u32 w0 = (u32)f2bf(f.x) | ((u32)f2bf(f.y) << 16);
    u32 w1 = (u32)f2bf(f.z) | ((u32)f2bf(f.w) << 16);
    *reinterpret_cast<uint2*>(out + (size_t)i * 4) = make_uint2(w0, w1);
  }
}

// W [K=512][N=1024] fp32 -> wt [N=1024][K=512] bf16 (transposed)
__global__ void convert_wt(const float* __restrict__ W, u16* __restrict__ wt) {
  int idx = blockIdx.x * blockDim.x + threadIdx.x;  // 65536 threads
  int n  = idx & 1023;
  int k0 = (idx >> 10) * 8;
  float f[8];
#pragma unroll
  for (int j = 0; j < 8; ++j) f[j] = W[(size_t)(k0 + j) * 1024 + n];
  u32 w[4];
#pragma unroll
  for (int j = 0; j < 4; ++j)
    w[j] = (u32)f2bf(f[2 * j]) | ((u32)f2bf(f[2 * j + 1]) << 16);
  *reinterpret_cast<uint4*>(wt + (size_t)n * 512 + k0) = make_uint4(w[0], w[1], w[2], w[3]);
}

// ---------------- GEMM (m97 structure) + fused activation + fused scan pass1 ----
// Block: 128 M-rows x 128 W-cols (= 64 d-channels: hidden + gate interleaved by
// the B-tile global row map so each wave owns matching hidden/gate pairs).
// 4 waves as 2x2; each wave: 64 rows x 64 cols = acc[4][4] of 16x16 frags.
// Bs row j -> W col: p=j>>5, w=j&31: gn = (p&1 ? 512:0) + d0 + (p>>1)*32 + w
//   wave (wr,wc): tile cols 64wc+16n+l15; n<2 hidden ch d0+32wc+16n+l15, gate=n+2.

#define BK 64

__global__ __launch_bounds__(256) void gemm_act(const u16* __restrict__ xb,
                                                const u16* __restrict__ wt,
                                                u16* __restrict__ a_buf,
                                                u16* __restrict__ v_buf,
                                                float* __restrict__ Asum,
                                                float* __restrict__ Bsum) {
  __shared__ u16 As[128 * BK];   // 16 KB, linear [row][k] rows of 64 bf16
  __shared__ u16 Bs[128 * BK];   // 16 KB

  const int tid  = threadIdx.x;
  const int lane = tid & 63;
  const int wave = tid >> 6;        // 0..3
  const int l15  = lane & 15;
  const int lh   = lane >> 4;       // 0..3
  const int wr   = wave >> 1;
  const int wc   = wave & 1;
  const int m_base = blockIdx.x * 128;
  const int d0     = blockIdx.y * 64;

  // staging geometry: per wave 4 calls each for A and B; call i covers 8 rows
  const int srow_in = lane >> 3;        // row within 8-row group
  const int sk      = (lane & 7) * 8;   // k elem offset (16B per lane)

  // B-tile global row map (per call, row = (wave*4+i)*8 + srow_in)
  int gnrow[4];
#pragma unroll
  for (int i = 0; i < 4; ++i) {
    int j = (wave * 4 + i) * 8 + srow_in;
    int p = j >> 5, w = j & 31;
    gnrow[i] = ((p & 1) ? 512 : 0) + d0 + ((p >> 1) << 5) + w;
  }
  int garow[4];
#pragma unroll
  for (int i = 0; i < 4; ++i) garow[i] = m_base + (wave * 4 + i) * 8 + srow_in;

  f32x4 acc[4][4];
#pragma unroll
  for (int m = 0; m < 4; ++m)
#pragma unroll
    for (int n = 0; n < 4; ++n)
      acc[m][n] = (f32x4){0.f, 0.f, 0.f, 0.f};

  for (int k0 = 0; k0 < K_DIM; k0 += BK) {
    __syncthreads();
#pragma unroll
    for (int i = 0; i < 4; ++i) {
      gload_lds16(xb + (size_t)garow[i] * K_DIM + k0 + sk, &As[(wave * 4 + i) * 8 * BK]);
      gload_lds16(wt + (size_t)gnrow[i] * K_DIM + k0 + sk, &Bs[(wave * 4 + i) * 8 * BK]);
    }
    __syncthreads();

#pragma unroll
    for (int kk = 0; kk < BK; kk += 32) {
      bf16x8 af[4], bfr[4];
#pragma unroll
      for (int m = 0; m < 4; ++m)
        af[m] = *reinterpret_cast<const bf16x8*>(&As[(64 * wr + m * 16 + l15) * BK + kk + lh * 8]);
#pragma unroll
      for (int n = 0; n < 4; ++n)
        bfr[n] = *reinterpret_cast<const bf16x8*>(&Bs[(64 * wc + n * 16 + l15) * BK + kk + lh * 8]);
#pragma unroll
      for (int m = 0; m < 4; ++m)
#pragma unroll
        for (int n = 0; n < 4; ++n)
          acc[m][n] = __builtin_amdgcn_mfma_f32_16x16x32_bf16(af[m], bfr[n], acc[m][n], 0, 0, 0);
    }
  }

  // ---- epilogue: a = sigmoid(-gate), v = sigmoid(gate)*g(hidden); write bf16;
  // ---- fused scan pass1: per 32-row chunk, (A,B) = chunk-composed affine map.
  const int row_w = m_base + 64 * wr;
#pragma unroll
  for (int h = 0; h < 2; ++h) {          // chunk half: rows [32h, 32h+32) of wave
    float Ar[2][2], Br[2][2];            // [n][mm]
#pragma unroll
    for (int mm = 0; mm < 2; ++mm) {
      const int m = 2 * h + mm;
#pragma unroll
      for (int n = 0; n < 2; ++n) {
        float A = 1.f, Bv = 0.f;
        const int dch = d0 + 32 * wc + 16 * n + l15;
#pragma unroll
        for (int r = 0; r < 4; ++r) {
          float hid = acc[m][n][r];
          float gt  = acc[m][n + 2][r];
          float e   = __expf(gt);
          float inv = 1.f / (1.f + e);         // a = sigmoid(-gate)
          float g   = (hid >= 0.f) ? (hid + 0.5f) : (1.f / (1.f + __expf(-hid)));
          float v   = (e * inv) * g;           // z * g
          u16 abf = f2bf(inv);
          u16 vbf = f2bf(v);
          const int grow = row_w + 16 * m + 4 * lh + r;
          a_buf[(size_t)grow * D_DIM + dch] = abf;
          v_buf[(size_t)grow * D_DIM + dch] = vbf;
          float af = bf2f(abf), vf = bf2f(vbf);
          Bv = af * Bv + vf;
          A *= af;
        }
        Ar[n][mm] = A; Br[n][mm] = Bv;
      }
    }
    // inclusive scan across lh (4 segments of 4 rows each), per (n, mm)
#pragma unroll
    for (int n = 0; n < 2; ++n)
#pragma unroll
      for (int mm = 0; mm < 2; ++mm) {
        float A = Ar[n][mm], Bv = Br[n][mm];
#pragma unroll
        for (int d = 1; d <= 2; d <<= 1) {
          float pA = __shfl(A, lane - 16 * d);
          float pB = __shfl(Bv, lane - 16 * d);
          if (lh >= d) { Bv = A * pB + Bv; A = A * pA; }
        }
        Ar[n][mm] = A; Br[n][mm] = Bv;
      }
    if (lh == 3) {   // lanes 48..63 hold full 16-row segment results
      const int grow = row_w + 32 * h;
      const int b = grow >> 13;           // / 8192
      const int c = (grow & 8191) >> 5;   // / 32
      const size_t o = ((size_t)(b * NC + c)) * D_DIM;
#pragma unroll
      for (int n = 0; n < 2; ++n) {
        const int dch = d0 + 32 * wc + 16 * n + l15;
        float Ac = Ar[n][0] * Ar[n][1];
        float Bc = Ar[n][1] * Br[n][0] + Br[n][1];
        Asum[o + dch] = Ac;
        Bsum[o + dch] = Bc;
      }
    }
  }
}

// ---------------- chunk-level serial scan (tiny) ----------------

__global__ __launch_bounds__(256) void scan_pass2(const float* __restrict__ Asum,
                                                  const float* __restrict__ Bsum,
                                                  float* __restrict__ carry) {
  int idx = blockIdx.x * blockDim.x + threadIdx.x;  // 2048 = B*D
  int b = idx >> 9;
  int d = idx & 511;
  float h = 0.f;
  for (int c = 0; c < NC; ++c) {
    size_t o = ((size_t)(b * NC + c)) * D_DIM + d;
    carry[o] = h;
    h = Asum[o] * h + Bsum[o];
  }
}

// ---------------- final within-chunk scan + output ----------------

__global__ __launch_bounds__(128) void scan_pass3(const u16* __restrict__ a_buf,
                                                  const u16* __restrict__ v_buf,
                                                  const float4* __restrict__ carry,
                                                  float4* __restrict__ out) {
  const int c = blockIdx.x;
  const int b = blockIdx.y;
  const int d4 = threadIdx.x;
  float4 hh = carry[((size_t)(b * NC + c)) * 128 + d4];
  float h[4] = {hh.x, hh.y, hh.z, hh.w};
  size_t base = ((size_t)b * T_DIM + (size_t)c * LCH) * D_DIM + d4 * 4;
  for (int t = 0; t < LCH; ++t) {
    uint2 aw = *reinterpret_cast<const uint2*>(a_buf + base);
    uint2 vw = *reinterpret_cast<const uint2*>(v_buf + base);
    float av[4] = {bf2f(aw.x & 0xffff), bf2f(aw.x >> 16), bf2f(aw.y & 0xffff), bf2f(aw.y >> 16)};
    float vv[4] = {bf2f(vw.x & 0xffff), bf2f(vw.x >> 16), bf2f(vw.y & 0xffff), bf2f(vw.y >> 16)};
#pragma unroll
    for (int j = 0; j < 4; ++j) h[j] = av[j] * h[j] + vv[j];
    out[base >> 2] = make_float4(h[0], h[1], h[2], h[3]);
    base += D_DIM;
  }
}

// ---------------- launch ----------------

extern "C" void kernel_launch(void* const* d_in, const int* in_sizes, int n_in,
                              void* d_out, int out_size, void* d_ws, size_t ws_size,
                              hipStream_t stream) {
  const float* x = (const float*)d_in[0];   // [4,8192,512]
  const float* W = (const float*)d_in[1];   // [512,1024]
  float* out = (float*)d_out;               // [4,8192,512]

  char* ws = (char*)d_ws;
  u16*   xb    = (u16*)(ws + 0);             // 33,554,432
  u16*   wtp   = (u16*)(ws + 33554432);      //  1,048,576
  u16*   a_buf = (u16*)(ws + 34603008);      // 33,554,432
  u16*   v_buf = (u16*)(ws + 68157440);      // 33,554,432
  float* Asum  = (float*)(ws + 101711872);   //  2,097,152
  float* Bsum  = (float*)(ws + 103809024);   //  2,097,152
  float* carry = (float*)(ws + 105906176);   //  2,097,152  (end 108,003,328)
  if (ws_size < 108003328ULL) return;

  convert_x<<<2048, 256, 0, stream>>>((const float4*)x, xb, (M_DIM * K_DIM) / 4);
  convert_wt<<<256, 256, 0, stream>>>(W, wtp);
  gemm_act<<<dim3(M_DIM / 128, D_DIM / 64), 256, 0, stream>>>(xb, wtp, a_buf, v_buf, Asum, Bsum);
  scan_pass2<<<8, 256, 0, stream>>>(Asum, Bsum, carry);
  scan_pass3<<<dim3(NC, B_DIM), 128, 0, stream>>>(a_buf, v_buf, (const float4*)carry, (float4*)out);
}

// Round 5
// 121.272 us; speedup vs baseline: 1.2652x; 1.1291x over previous
//
#include <hip/hip_runtime.h>

typedef unsigned short u16;
typedef unsigned int   u32;

typedef __bf16 bf16x8 __attribute__((ext_vector_type(8)));
typedef float  f32x4  __attribute__((ext_vector_type(4)));

#define B_DIM 4
#define T_DIM 8192
#define D_DIM 512
#define M_DIM (B_DIM * T_DIM)   // 32768
#define K_DIM D_DIM             // 512
#define NC    256               // chunks along T
#define LCH   32                // chunk length (NC*LCH == T_DIM)

__device__ __forceinline__ u16 f2bf(float f) {
  u32 u = __float_as_uint(f);
  u32 r = (u + 0x7FFFu + ((u >> 16) & 1u)) >> 16;   // RNE
  return (u16)r;
}
__device__ __forceinline__ float bf2f(u16 b) {
  return __uint_as_float(((u32)b) << 16);
}

// async global->LDS, 16B per lane; lds dest is wave-uniform base + lane*16
__device__ __forceinline__ void gload_lds16(const u16* g, u16* lds) {
  __builtin_amdgcn_global_load_lds(
      (const __attribute__((address_space(1))) void*)g,
      (__attribute__((address_space(3))) void*)lds, 16, 0, 0);
}

// ---------------- conversion kernels ----------------

__global__ void convert_x(const float4* __restrict__ in, u16* __restrict__ out, int n4) {
  int i = blockIdx.x * blockDim.x + threadIdx.x;
  int stride = gridDim.x * blockDim.x;
  for (; i < n4; i += stride) {
    float4 f = in[i];
    u32 w0 = (u32)f2bf(f.x) | ((u32)f2bf(f.y) << 16);
    u32 w1 = (u32)f2bf(f.z) | ((u32)f2bf(f.w) << 16);
    *reinterpret_cast<uint2*>(out + (size_t)i * 4) = make_uint2(w0, w1);
  }
}

// W [K=512][N=1024] fp32 -> wt [N=1024][K=512] bf16 (transposed)
__global__ void convert_wt(const float* __restrict__ W, u16* __restrict__ wt) {
  int idx = blockIdx.x * blockDim.x + threadIdx.x;  // 65536 threads
  int n  = idx & 1023;
  int k0 = (idx >> 10) * 8;
  float f[8];
#pragma unroll
  for (int j = 0; j < 8; ++j) f[j] = W[(size_t)(k0 + j) * 1024 + n];
  u32 w[4];
#pragma unroll
  for (int j = 0; j < 4; ++j)
    w[j] = (u32)f2bf(f[2 * j]) | ((u32)f2bf(f[2 * j + 1]) << 16);
  *reinterpret_cast<uint4*>(wt + (size_t)n * 512 + k0) = make_uint4(w[0], w[1], w[2], w[3]);
}

// ---------------- GEMM (dbuf stage-early + T2 swizzle) + act + scan pass1 ----
// Block: 128 M-rows x 128 W-cols (64 channels: hidden rows 0-31/64-95, gate
// rows 32-63/96-127 of the B tile). 4 waves as 2x2; wave = 64 rows x 64 cols,
// acc[4][4]; pairing hidden=acc[m][n], gate=acc[m][n+2], ch = d0+32*wc+16n+l15.
// LDS layout: [row][slot] of 16B slots, slot_phys = slot_log ^ (row&7) (XOR
// swizzle via pre-swizzled GLOBAL source, linear gload_lds dest — rule #21).

#define BK 64
#define NT (K_DIM / BK)   // 8

__global__ __launch_bounds__(256) void gemm_act(const u16* __restrict__ xb,
                                                const u16* __restrict__ wt,
                                                u32* __restrict__ av_buf,
                                                float* __restrict__ Asum,
                                                float* __restrict__ Bsum) {
  __shared__ u16 As[2][128 * BK];   // 2 x 16 KB
  __shared__ u16 Bs[2][128 * BK];   // 2 x 16 KB

  const int tid  = threadIdx.x;
  const int lane = tid & 63;
  const int wave = tid >> 6;        // 0..3
  const int l15  = lane & 15;
  const int lh   = lane >> 4;       // 0..3
  const int wr   = wave >> 1;
  const int wc   = wave & 1;
  const int m_base = blockIdx.x * 128;
  const int d0     = blockIdx.y * 64;

  // staging: 4 calls, call i covers rows i*32 + (tid>>3), slot tid&7
  const int srow = tid >> 3;                         // 0..31
  const int sk   = (((tid & 7) ^ (srow & 7)) << 3);  // swizzled k-elem offset

  int garow[4], gnrow[4];
#pragma unroll
  for (int i = 0; i < 4; ++i) {
    garow[i] = m_base + i * 32 + srow;
    // B row j = i*32+srow: i&1 -> gate half; i>>1 -> channel 32-block
    gnrow[i] = ((i & 1) ? 512 : 0) + d0 + ((i >> 1) << 5) + srow;
  }
  const int lds_w = wave * 512;   // elem offset of this wave's 1KB within a call

  f32x4 acc[4][4];
#pragma unroll
  for (int m = 0; m < 4; ++m)
#pragma unroll
    for (int n = 0; n < 4; ++n)
      acc[m][n] = (f32x4){0.f, 0.f, 0.f, 0.f};

#define STAGE(buf, kofs)                                                        \
  do {                                                                          \
    _Pragma("unroll")                                                           \
    for (int i = 0; i < 4; ++i) {                                               \
      gload_lds16(xb + (size_t)garow[i] * K_DIM + (kofs) + sk,                  \
                  &As[buf][i * 2048 + lds_w]);                                  \
      gload_lds16(wt + (size_t)gnrow[i] * K_DIM + (kofs) + sk,                  \
                  &Bs[buf][i * 2048 + lds_w]);                                  \
    }                                                                           \
  } while (0)

  STAGE(0, 0);
  int cur = 0;
  for (int t = 0; t < NT; ++t) {
    __syncthreads();               // drains prior stage (one compute-phase old)
    if (t + 1 < NT) STAGE(cur ^ 1, (t + 1) * BK);
#pragma unroll
    for (int kk = 0; kk < 2; ++kk) {
      bf16x8 af[4], bfr[4];
#pragma unroll
      for (int m = 0; m < 4; ++m) {
        int r = 64 * wr + m * 16 + l15;
        int slot = (4 * kk + lh) ^ (l15 & 7);
        af[m] = *reinterpret_cast<const bf16x8*>(&As[cur][r * 64 + slot * 8]);
      }
#pragma unroll
      for (int n = 0; n < 4; ++n) {
        int r = 64 * wc + n * 16 + l15;
        int slot = (4 * kk + lh) ^ (l15 & 7);
        bfr[n] = *reinterpret_cast<const bf16x8*>(&Bs[cur][r * 64 + slot * 8]);
      }
#pragma unroll
      for (int m = 0; m < 4; ++m)
#pragma unroll
        for (int n = 0; n < 4; ++n)
          acc[m][n] = __builtin_amdgcn_mfma_f32_16x16x32_bf16(af[m], bfr[n], acc[m][n], 0, 0, 0);
    }
    cur ^= 1;
  }
#undef STAGE

  // ---- epilogue: a = sigmoid(-gate), v = sigmoid(gate)*g(hidden); av packed;
  // ---- fused scan pass1: per 32-row chunk, (A,B) = chunk-composed affine map.
  const int row_w = m_base + 64 * wr;
#pragma unroll
  for (int h = 0; h < 2; ++h) {          // chunk half: rows [32h, 32h+32) of wave
    float Ar[2][2], Br[2][2];            // [n][mm]
#pragma unroll
    for (int mm = 0; mm < 2; ++mm) {
      const int m = 2 * h + mm;
#pragma unroll
      for (int n = 0; n < 2; ++n) {
        float A = 1.f, Bv = 0.f;
        const int dch = d0 + 32 * wc + 16 * n + l15;
#pragma unroll
        for (int r = 0; r < 4; ++r) {
          float hid = acc[m][n][r];
          float gt  = acc[m][n + 2][r];
          float e   = __expf(gt);
          float inv = 1.f / (1.f + e);         // a = sigmoid(-gate)
          float g   = (hid >= 0.f) ? (hid + 0.5f) : (1.f / (1.f + __expf(-hid)));
          float v   = (e * inv) * g;           // z * g
          u16 abf = f2bf(inv);
          u16 vbf = f2bf(v);
          const int grow = row_w + 16 * m + 4 * lh + r;
          av_buf[(size_t)grow * D_DIM + dch] = (u32)abf | ((u32)vbf << 16);
          float af = bf2f(abf), vf = bf2f(vbf);
          Bv = af * Bv + vf;
          A *= af;
        }
        Ar[n][mm] = A; Br[n][mm] = Bv;
      }
    }
    // inclusive scan across lh (4 segments of 4 rows each), per (n, mm)
#pragma unroll
    for (int n = 0; n < 2; ++n)
#pragma unroll
      for (int mm = 0; mm < 2; ++mm) {
        float A = Ar[n][mm], Bv = Br[n][mm];
#pragma unroll
        for (int d = 1; d <= 2; d <<= 1) {
          float pA = __shfl(A, lane - 16 * d);
          float pB = __shfl(Bv, lane - 16 * d);
          if (lh >= d) { Bv = A * pB + Bv; A = A * pA; }
        }
        Ar[n][mm] = A; Br[n][mm] = Bv;
      }
    if (lh == 3) {   // lanes 48..63 hold full 16-row segment results
      const int grow = row_w + 32 * h;
      const int b = grow >> 13;           // / 8192
      const int c = (grow & 8191) >> 5;   // / 32
      const size_t o = ((size_t)(b * NC + c)) * D_DIM;
#pragma unroll
      for (int n = 0; n < 2; ++n) {
        const int dch = d0 + 32 * wc + 16 * n + l15;
        float Ac = Ar[n][0] * Ar[n][1];
        float Bc = Ar[n][1] * Br[n][0] + Br[n][1];
        Asum[o + dch] = Ac;
        Bsum[o + dch] = Bc;
      }
    }
  }
}

// ---------------- chunk-level serial scan (tiny) ----------------

__global__ __launch_bounds__(256) void scan_pass2(const float* __restrict__ Asum,
                                                  const float* __restrict__ Bsum,
                                                  float* __restrict__ carry) {
  int idx = blockIdx.x * blockDim.x + threadIdx.x;  // 2048 = B*D
  int b = idx >> 9;
  int d = idx & 511;
  float h = 0.f;
  for (int c = 0; c < NC; ++c) {
    size_t o = ((size_t)(b * NC + c)) * D_DIM + d;
    carry[o] = h;
    h = Asum[o] * h + Bsum[o];
  }
}

// ---------------- final within-chunk scan + output ----------------

__global__ __launch_bounds__(128) void scan_pass3(const u32* __restrict__ av_buf,
                                                  const float4* __restrict__ carry,
                                                  float4* __restrict__ out) {
  const int c = blockIdx.x;
  const int b = blockIdx.y;
  const int d4 = threadIdx.x;
  float4 hh = carry[((size_t)(b * NC + c)) * 128 + d4];
  float h[4] = {hh.x, hh.y, hh.z, hh.w};
  size_t base = ((size_t)b * T_DIM + (size_t)c * LCH) * D_DIM + d4 * 4;
  for (int t = 0; t < LCH; ++t) {
    uint4 w = *reinterpret_cast<const uint4*>(av_buf + base);
    h[0] = bf2f(w.x & 0xffff) * h[0] + bf2f(w.x >> 16);
    h[1] = bf2f(w.y & 0xffff) * h[1] + bf2f(w.y >> 16);
    h[2] = bf2f(w.z & 0xffff) * h[2] + bf2f(w.z >> 16);
    h[3] = bf2f(w.w & 0xffff) * h[3] + bf2f(w.w >> 16);
    out[base >> 2] = make_float4(h[0], h[1], h[2], h[3]);
    base += D_DIM;
  }
}

// ---------------- launch ----------------

extern "C" void kernel_launch(void* const* d_in, const int* in_sizes, int n_in,
                              void* d_out, int out_size, void* d_ws, size_t ws_size,
                              hipStream_t stream) {
  const float* x = (const float*)d_in[0];   // [4,8192,512]
  const float* W = (const float*)d_in[1];   // [512,1024]
  float* out = (float*)d_out;               // [4,8192,512]

  char* ws = (char*)d_ws;
  u16*   xb     = (u16*)(ws + 0);             // 33,554,432
  u16*   wtp    = (u16*)(ws + 33554432);      //  1,048,576
  u32*   av_buf = (u32*)(ws + 34603008);      // 67,108,864 (a lo16 | v hi16)
  float* Asum   = (float*)(ws + 101711872);   //  2,097,152
  float* Bsum   = (float*)(ws + 103809024);   //  2,097,152
  float* carry  = (float*)(ws + 105906176);   //  2,097,152  (end 108,003,328)
  if (ws_size < 108003328ULL) return;

  convert_x<<<2048, 256, 0, stream>>>((const float4*)x, xb, (M_DIM * K_DIM) / 4);
  convert_wt<<<256, 256, 0, stream>>>(W, wtp);
  gemm_act<<<dim3(M_DIM / 128, D_DIM / 64), 256, 0, stream>>>(xb, wtp, av_buf, Asum, Bsum);
  scan_pass2<<<8, 256, 0, stream>>>(Asum, Bsum, carry);
  scan_pass3<<<dim3(NC, B_DIM), 128, 0, stream>>>(av_buf, (const float4*)carry, (float4*)out);
}